// Round 1
// baseline (1426.800 us; speedup 1.0000x reference)
//
#include <hip/hip_runtime.h>
#include <stdint.h>

#define K_NEIGH 20
#define THRES   0.5f
#define NPTS    4096
#define BLOCK   256
#define CAP     256   // LDS candidate capacity (mean 82 below T=0.02, P(>256) ~ 0)

__global__ __launch_bounds__(BLOCK)
void knn_topk_kernel(const float* __restrict__ x, int* __restrict__ out) {
    const int row  = blockIdx.x;            // b*4096 + i
    const int self = row & (NPTS - 1);      // self index within the row's matrix
    const int tid  = threadIdx.x;
    const float* __restrict__ xr = x + (size_t)row * NPTS;

    // Register cache: 16 values/thread, 4x float4 fully-coalesced (16 B/lane).
    // Element index of v[4*m+j] is 4*tid + 1024*m + j.
    float v[16];
#pragma unroll
    for (int m = 0; m < 4; ++m) {
        float4 f = ((const float4*)xr)[tid + 256 * m];
        v[4*m+0] = f.x; v[4*m+1] = f.y; v[4*m+2] = f.z; v[4*m+3] = f.w;
    }

    __shared__ unsigned long long keys[CAP];
    __shared__ int cnt;
    __shared__ unsigned long long warpmin[4];

    if (tid == 0) cnt = 0;
    __syncthreads();

    // ---- Fast path: collect candidates < T into LDS as packed sortable keys.
    // key = (fp32 bits << 32) | element index  -> min == (min value, min index)
    const float T = 0.02f;
    int local = 0;
#pragma unroll
    for (int e = 0; e < 16; ++e) local += (v[e] < T) ? 1 : 0;

    int base = 0;
    if (local) base = atomicAdd(&cnt, local);
    if (local && base + local <= CAP) {
        int o = base;
#pragma unroll
        for (int m = 0; m < 4; ++m) {
#pragma unroll
            for (int j = 0; j < 4; ++j) {
                float val = v[4*m + j];
                if (val < T) {
                    unsigned idx = 4u*tid + 1024u*m + j;
                    keys[o++] = ((unsigned long long)__float_as_uint(val) << 32) | idx;
                }
            }
        }
    }
    __syncthreads();
    const int total = cnt;   // block-uniform

    if (total >= K_NEIGH && total <= CAP) {
        // Pad to CAP with +inf keys, then bitonic sort 256 keys ascending.
        if (tid >= total) keys[tid] = ~0ULL;
        __syncthreads();
        for (int k = 2; k <= CAP; k <<= 1) {
            for (int j = k >> 1; j > 0; j >>= 1) {
                int ixj = tid ^ j;
                if (ixj > tid) {
                    unsigned long long a = keys[tid];
                    unsigned long long b = keys[ixj];
                    bool up = ((tid & k) == 0);
                    if ((a > b) == up) { keys[tid] = b; keys[ixj] = a; }
                }
                __syncthreads();
            }
        }
        if (tid < K_NEIGH) {
            unsigned long long kk = keys[tid];
            float val = __uint_as_float((unsigned)(kk >> 32));
            int   idx = (int)(kk & 0xFFFFFFFFu);
            out[(size_t)row * K_NEIGH + tid] = (val > THRES) ? self : idx;
        }
    } else {
        // ---- Exact fallback (statistically never taken; fully general):
        // 20 iterations of block-wide argmin over the register cache, with
        // invalidation-by-index. Reproduces stable top_k on any input.
        for (int sel = 0; sel < K_NEIGH; ++sel) {
            unsigned long long best = ~0ULL;
#pragma unroll
            for (int m = 0; m < 4; ++m) {
#pragma unroll
                for (int j = 0; j < 4; ++j) {
                    unsigned long long kk =
                        ((unsigned long long)__float_as_uint(v[4*m + j]) << 32) |
                        (4u*tid + 1024u*m + j);
                    if (kk < best) best = kk;
                }
            }
            // wave (64-lane) shuffle reduce
            for (int off = 32; off; off >>= 1) {
                unsigned long long o = __shfl_down(best, off);
                if (o < best) best = o;
            }
            if ((tid & 63) == 0) warpmin[tid >> 6] = best;
            __syncthreads();
            if (tid == 0) {
                unsigned long long b0 = warpmin[0];
                for (int w = 1; w < 4; ++w) if (warpmin[w] < b0) b0 = warpmin[w];
                warpmin[0] = b0;
            }
            __syncthreads();
            unsigned long long win = warpmin[0];
            if (tid == 0) {
                float val = __uint_as_float((unsigned)(win >> 32));
                int   idx = (int)(win & 0xFFFFFFFFu);
                out[(size_t)row * K_NEIGH + sel] = (val > THRES) ? self : idx;
            }
            // invalidate exactly the winning element (by index) in its owner's regs
            unsigned widx  = (unsigned)(win & 0xFFFFFFFFu);
            int      owner = (int)((widx >> 2) & 255u);
            if (tid == owner) v[4*(widx >> 10) + (widx & 3u)] = __uint_as_float(0x7F800000u);
            __syncthreads();   // protect warpmin reuse next iteration
        }
    }
}

extern "C" void kernel_launch(void* const* d_in, const int* in_sizes, int n_in,
                              void* d_out, int out_size, void* d_ws, size_t ws_size,
                              hipStream_t stream) {
    const float* x  = (const float*)d_in[0];
    int*        out = (int*)d_out;
    const int n_rows = in_sizes[0] / NPTS;   // 16*4096 = 65536
    knn_topk_kernel<<<n_rows, BLOCK, 0, stream>>>(x, out);
}

// Round 2
// 1348.917 us; speedup vs baseline: 1.0577x; 1.0577x over previous
//
#include <hip/hip_runtime.h>
#include <stdint.h>

#define K_NEIGH 20
#define THRES   0.5f
#define NPTS    4096
#define WAVES   4          // waves per block, one row per wave
#define BLOCK   (64 * WAVES)
#define CAP     256        // per-row candidate capacity (mean 82 at T=0.02; 256 is ~19 sigma)
#define TCAND   0.02f      // candidate threshold: E[count]=82, P(<20) ~ 3e-12, P(>256) ~ 0

__global__ __launch_bounds__(BLOCK, 4)
void knn_topk_wave(const float* __restrict__ x, int* __restrict__ out) {
    const int wave = threadIdx.x >> 6;
    const int lane = threadIdx.x & 63;
    const int row  = blockIdx.x * WAVES + wave;      // b*4096 + i, 65536 rows
    const int self = row & (NPTS - 1);
    const float* __restrict__ xr = x + (size_t)row * NPTS;

    // Per-wave private LDS: no cross-wave sharing -> ZERO __syncthreads in kernel.
    __shared__ unsigned long long keys[WAVES][CAP];
    __shared__ int cnt[WAVES];

    if (lane == 0) cnt[wave] = 0;   // wave-lockstep + in-order LDS pipe: ordered vs atomics below

    // ---- Load the whole row: 16 x float4 per lane, 1 KB/instruction coalesced.
    // Element index of f[m] component j is 4*(lane + 64*m) + j.
    float4 f[16];
#pragma unroll
    for (int m = 0; m < 16; ++m) f[m] = ((const float4*)xr)[lane + 64 * m];

    // ---- Count candidates below T.
    int local = 0;
#pragma unroll
    for (int m = 0; m < 16; ++m) {
        local += (f[m].x < TCAND) + (f[m].y < TCAND) +
                 (f[m].z < TCAND) + (f[m].w < TCAND);
    }

    // ---- Wave-local scatter into LDS as packed sortable keys:
    // key = (fp32 bits << 32) | index  -> ascending key == ascending (value, index).
    int base = 0;
    if (local) base = atomicAdd(&cnt[wave], local);
    if (local && base + local <= CAP) {
        int o = base;
#pragma unroll
        for (int m = 0; m < 16; ++m) {
            const unsigned eb = 4u * ((unsigned)lane + 64u * m);
            const float vv[4] = { f[m].x, f[m].y, f[m].z, f[m].w };
#pragma unroll
            for (int j = 0; j < 4; ++j) {
                if (vv[j] < TCAND) {
                    keys[wave][o++] =
                        ((unsigned long long)__float_as_uint(vv[j]) << 32) | (eb + j);
                }
            }
        }
    }

    const int C = cnt[wave];   // wave-uniform; atomics precede in wave program order
    unsigned long long mine = ~0ULL;

    if (C >= K_NEIGH && C <= CAP) {
        // ---- Fast path: 4 candidate keys per lane in registers, then 20 x
        // (lane-min -> xor-butterfly wave-min -> invalidate winner). No barriers.
        unsigned long long s0 = (lane       < C) ? keys[wave][lane      ] : ~0ULL;
        unsigned long long s1 = (lane + 64  < C) ? keys[wave][lane + 64 ] : ~0ULL;
        unsigned long long s2 = (lane + 128 < C) ? keys[wave][lane + 128] : ~0ULL;
        unsigned long long s3 = (lane + 192 < C) ? keys[wave][lane + 192] : ~0ULL;
#pragma unroll
        for (int sel = 0; sel < K_NEIGH; ++sel) {
            unsigned long long a0 = (s0 < s1) ? s0 : s1;
            unsigned long long a1 = (s2 < s3) ? s2 : s3;
            unsigned long long b  = (a0 < a1) ? a0 : a1;
#pragma unroll
            for (int off = 1; off < 64; off <<= 1) {
                unsigned long long o = __shfl_xor(b, off);
                b = (o < b) ? o : b;
            }
            // exact invalidation: keys are unique (index in low bits)
            if (s0 == b) s0 = ~0ULL;
            if (s1 == b) s1 = ~0ULL;
            if (s2 == b) s2 = ~0ULL;
            if (s3 == b) s3 = ~0ULL;
            if (lane == sel) mine = b;
        }
    } else {
        // ---- Exact fallback (wave-uniform branch; statistically never taken):
        // 20 x wave-argmin over ALL 64 values/lane (still in registers), with
        // strictly-increasing-key exclusion. Stable top_k on any input.
        unsigned long long prev = 0ULL;
        bool first = true;
        for (int sel = 0; sel < K_NEIGH; ++sel) {
            unsigned long long b = ~0ULL;
#pragma unroll
            for (int m = 0; m < 16; ++m) {
                const unsigned eb = 4u * ((unsigned)lane + 64u * m);
                const float vv[4] = { f[m].x, f[m].y, f[m].z, f[m].w };
#pragma unroll
                for (int j = 0; j < 4; ++j) {
                    unsigned long long kk =
                        ((unsigned long long)__float_as_uint(vv[j]) << 32) | (eb + j);
                    if ((first || kk > prev) && kk < b) b = kk;
                }
            }
            for (int off = 1; off < 64; off <<= 1) {
                unsigned long long o = __shfl_xor(b, off);
                b = (o < b) ? o : b;
            }
            prev = b; first = false;
            if (lane == sel) mine = b;
        }
    }

    // ---- Epilogue: lanes 0..19 write their rank's index (threshold -> self).
    if (lane < K_NEIGH) {
        float val = __uint_as_float((unsigned)(mine >> 32));
        int   idx = (int)(mine & 0xFFFFFFFFu);
        out[(size_t)row * K_NEIGH + lane] = (val > THRES) ? self : idx;
    }
}

extern "C" void kernel_launch(void* const* d_in, const int* in_sizes, int n_in,
                              void* d_out, int out_size, void* d_ws, size_t ws_size,
                              hipStream_t stream) {
    const float* x  = (const float*)d_in[0];
    int*        out = (int*)d_out;
    const int n_rows  = in_sizes[0] / NPTS;          // 65536
    const int n_blocks = n_rows / WAVES;             // 16384
    knn_topk_wave<<<n_blocks, BLOCK, 0, stream>>>(x, out);
}

// Round 3
// 1343.586 us; speedup vs baseline: 1.0619x; 1.0040x over previous
//
#include <hip/hip_runtime.h>
#include <stdint.h>

#define K_NEIGH 20
#define THRES   0.5f
#define NPTS    4096
#define WAVES   4          // waves per block, one row per wave
#define BLOCK   (64 * WAVES)
#define CAP     256        // per-row candidate capacity (mean 82 at T=0.02; ~19 sigma)
#define TCAND   0.02f      // E[count]=82; P(<20) ~ 3e-12, P(>256) ~ 0 per row

// Streamed, double-buffered variant: 4 float4/lane per stage (32 buffer VGPRs
// instead of 64 for a full row cache) -> ~6 waves/SIMD instead of 4, more
// loads in flight. Zero __syncthreads (wave-private LDS regions only).
__global__ __launch_bounds__(BLOCK, 6)
void knn_topk_stream(const float* __restrict__ x, int* __restrict__ out) {
    const int wave = threadIdx.x >> 6;
    const int lane = threadIdx.x & 63;
    const int row  = blockIdx.x * WAVES + wave;      // b*4096 + i
    const int self = row & (NPTS - 1);
    const float4* __restrict__ xr4 = (const float4*)(x + (size_t)row * NPTS);

    __shared__ unsigned long long keys[WAVES][CAP];
    __shared__ int cnt[WAVES];
    if (lane == 0) cnt[wave] = 0;   // wave-lockstep; DS ops in program order

    // ---- Streaming filter: 4 stages x (4 float4/lane), double-buffered so
    // stage g+1's loads are in flight while stage g is filtered into LDS.
    float4 bufA[4], bufB[4];
#pragma unroll
    for (int m = 0; m < 4; ++m) bufA[m] = xr4[lane + 64 * m];

#pragma unroll 1
    for (int g = 0; g < 4; ++g) {
        if (g < 3) {
#pragma unroll
            for (int m = 0; m < 4; ++m) bufB[m] = xr4[lane + 64 * (4 * (g + 1) + m)];
        }
        int local = 0;
#pragma unroll
        for (int m = 0; m < 4; ++m) {
            local += (bufA[m].x < TCAND) + (bufA[m].y < TCAND) +
                     (bufA[m].z < TCAND) + (bufA[m].w < TCAND);
        }
        int o = 0;
        if (local) o = atomicAdd(&cnt[wave], local);
        if (local && o + local <= CAP) {
#pragma unroll
            for (int m = 0; m < 4; ++m) {
                const unsigned eb = 4u * ((unsigned)lane + 64u * (4 * g + m));
                const float vv[4] = { bufA[m].x, bufA[m].y, bufA[m].z, bufA[m].w };
#pragma unroll
                for (int j = 0; j < 4; ++j) {
                    if (vv[j] < TCAND) {
                        keys[wave][o++] =
                            ((unsigned long long)__float_as_uint(vv[j]) << 32) | (eb + j);
                    }
                }
            }
        }
#pragma unroll
        for (int m = 0; m < 4; ++m) bufA[m] = bufB[m];
    }

    const int C = cnt[wave];   // wave-uniform
    unsigned long long mine = ~0ULL;

    if (C >= K_NEIGH && C <= CAP) {
        // ---- Fast path: up to 4 candidate keys/lane in registers, then 20 x
        // (lane-min -> 6-step xor-butterfly wave-min -> invalidate winner).
        unsigned long long s0 = (lane       < C) ? keys[wave][lane      ] : ~0ULL;
        unsigned long long s1 = (lane + 64  < C) ? keys[wave][lane + 64 ] : ~0ULL;
        unsigned long long s2 = (lane + 128 < C) ? keys[wave][lane + 128] : ~0ULL;
        unsigned long long s3 = (lane + 192 < C) ? keys[wave][lane + 192] : ~0ULL;
#pragma unroll
        for (int sel = 0; sel < K_NEIGH; ++sel) {
            unsigned long long a0 = (s0 < s1) ? s0 : s1;
            unsigned long long a1 = (s2 < s3) ? s2 : s3;
            unsigned long long b  = (a0 < a1) ? a0 : a1;
#pragma unroll
            for (int off = 1; off < 64; off <<= 1) {
                unsigned long long o = __shfl_xor(b, off);
                b = (o < b) ? o : b;
            }
            if (s0 == b) s0 = ~0ULL;   // keys unique (index in low bits)
            if (s1 == b) s1 = ~0ULL;
            if (s2 == b) s2 = ~0ULL;
            if (s3 == b) s3 = ~0ULL;
            if (lane == sel) mine = b;
        }
    } else {
        // ---- Exact fallback (wave-uniform; statistically never taken).
        // Re-reads the row from global each round (L2-resident after pass 1);
        // keeps the hot path's register footprint small. Stable top_k exact.
        unsigned long long prev = 0ULL;
        bool first = true;
        for (int sel = 0; sel < K_NEIGH; ++sel) {
            unsigned long long b = ~0ULL;
            for (int m = 0; m < 16; ++m) {
                float4 fv = xr4[lane + 64 * m];
                const unsigned eb = 4u * ((unsigned)lane + 64u * m);
                const float vv[4] = { fv.x, fv.y, fv.z, fv.w };
#pragma unroll
                for (int j = 0; j < 4; ++j) {
                    unsigned long long kk =
                        ((unsigned long long)__float_as_uint(vv[j]) << 32) | (eb + j);
                    if ((first || kk > prev) && kk < b) b = kk;
                }
            }
            for (int off = 1; off < 64; off <<= 1) {
                unsigned long long o = __shfl_xor(b, off);
                b = (o < b) ? o : b;
            }
            prev = b; first = false;
            if (lane == sel) mine = b;
        }
    }

    // ---- Epilogue: lanes 0..19 write their rank's index (threshold -> self).
    if (lane < K_NEIGH) {
        float val = __uint_as_float((unsigned)(mine >> 32));
        int   idx = (int)(mine & 0xFFFFFFFFu);
        out[(size_t)row * K_NEIGH + lane] = (val > THRES) ? self : idx;
    }
}

extern "C" void kernel_launch(void* const* d_in, const int* in_sizes, int n_in,
                              void* d_out, int out_size, void* d_ws, size_t ws_size,
                              hipStream_t stream) {
    const float* x  = (const float*)d_in[0];
    int*        out = (int*)d_out;
    const int n_rows   = in_sizes[0] / NPTS;         // 65536
    const int n_blocks = n_rows / WAVES;             // 16384
    knn_topk_stream<<<n_blocks, BLOCK, 0, stream>>>(x, out);
}